// Round 2
// 304.040 us; speedup vs baseline: 1.0048x; 1.0048x over previous
//
#include <hip/hip_runtime.h>

// Self-attention fwd: B=4, S=2048, D=1024, single head.
// Round 10: fix R9's 8-phase schedule race. R9 staged tile(2i+2) into buf0
// during phases 1-3 while buf0 was still being read (async LDS writes land
// any time after issue -> corruption, absmax 8e-2). New discipline: a slot's
// stage is issued only AFTER the barrier following that slot's last read:
//   per half-iteration T (buf=T&1, consuming tile T):
//     pq0: ds-read aF(rows 0-63) + ALL bF (B liveness ends at pq1 MFMA);
//          stage (T+1, A-h1) -> buf^1 (reads ended last half-iter)
//     pq1: MFMA only
//     pq2: ds-read aF(rows 64-127); stage (T+2, B-h0/B-h1) (B free since pq1)
//     pq3: stage (T+2, A-h0) (A free since pq2); vmcnt(6) -> tile T+1
//          resident, 3 half-tiles in flight (m201 steady state); tail vmcnt(0)
// Swizzle upgraded to 3-bit: byte ^= ((byte>>7)&7)<<4 (chunk bits 4-6 XOR row
// bits 0-2) -> 2 lanes/bank on ds_read_b128 (free), vs R9's 1-bit (8-way).
// Epilogues + associativity rewrite out = P @ (V*Wo) kept from R8.
//
// ws layout (bf16-element offsets over (u16*)d_ws):
//   xb    @ 0          (8388608)   <- VWoT after QKV (xb dead)  [b][do][s]
//   qkv   @ 8388608    (25165824)  [8192][3072] (q|k|v interleaved by col)
//   E     @ 33554432   (16777216)  exp(logits) bf16
//   wqkvT @ 50331648   (3145728)   [3072][1024]  (wqT|wkT|wvT)
//   woT   @ 53477376   (1048576)
//   bqkv  @ 54525952   (6144 u16 = 3072 fp32)
//   l     @ 54532096   (16384 u16 = 8192 fp32 row sums)   end = 109.1 MB

typedef unsigned short u16;
typedef short bf16x8 __attribute__((ext_vector_type(8)));
typedef float f32x4 __attribute__((ext_vector_type(4)));

#define SEQ 2048
#define DIM 1024

__device__ __forceinline__ u16 f2bf(float f) {
    unsigned u = __builtin_bit_cast(unsigned, f);
    u += 0x7fffu + ((u >> 16) & 1u);
    return (u16)(u >> 16);
}

// async 16B global -> LDS (wave-uniform LDS base + lane*16 by construction)
__device__ __forceinline__ void async16(void* lds, const void* gmem) {
    __builtin_amdgcn_global_load_lds(
        (const __attribute__((address_space(1))) void*)gmem,
        (__attribute__((address_space(3))) void*)lds, 16, 0, 0);
}

// ---------------------------------------------------------------------------
// cast x fp32 -> bf16 (blocks 0..8191); bias concat + zero l (blocks 8192+)
__global__ __launch_bounds__(256) void cast_x_kernel(
    const float* __restrict__ x, u16* __restrict__ xb,
    const float* __restrict__ bq, const float* __restrict__ bk,
    const float* __restrict__ bv, float* __restrict__ bqkv,
    float* __restrict__ l)
{
    const int b = blockIdx.x;
    if (b < 8192) {
        const int idx = b * 256 + threadIdx.x;
        float4 v = ((const float4*)x)[idx];
        ushort4 o;
        o.x = f2bf(v.x); o.y = f2bf(v.y); o.z = f2bf(v.z); o.w = f2bf(v.w);
        ((ushort4*)xb)[idx] = o;
    } else {
        const int i = (b - 8192) * 256 + threadIdx.x;   // 0..11263
        if (i < 3072)
            bqkv[i] = (i < 1024) ? bq[i] : (i < 2048) ? bk[i - 1024] : bv[i - 2048];
        else if (i < 3072 + 8192)
            l[i - 3072] = 0.f;
    }
}

// transpose+cast all four 1024x1024 fp32 weights -> bf16 WT[n][k]; z picks W.
__global__ __launch_bounds__(256) void transpose_cast_all(
    const float* __restrict__ W0, const float* __restrict__ W1,
    const float* __restrict__ W2, const float* __restrict__ W3,
    u16* __restrict__ Tqkv, u16* __restrict__ To)
{
    __shared__ float tile[32][33];
    const int z = blockIdx.z;
    const float* W = (z == 0) ? W0 : (z == 1) ? W1 : (z == 2) ? W2 : W3;
    u16* T = (z < 3) ? (Tqkv + (size_t)z * 1048576) : To;

    const int bx = blockIdx.x * 32, by = blockIdx.y * 32;
    const int tx = threadIdx.x, ty = threadIdx.y;
    #pragma unroll
    for (int r = 0; r < 4; ++r)
        tile[ty + r * 8][tx] = W[(size_t)(by + ty + r * 8) * DIM + bx + tx];
    __syncthreads();
    #pragma unroll
    for (int r = 0; r < 4; ++r) {
        const float v = tile[tx][ty + r * 8];   // = W[by+tx][bx+ty+r*8]
        T[(size_t)(bx + ty + r * 8) * DIM + by + tx] = f2bf(v);
    }
}

// ---------------------------------------------------------------------------
// 256x256 8-wave 8-phase GEMM: A[M,K] @ Bt[N,K]^T.
#define EPI_BF16BIAS 0  // bf16 store of a+bias[col]
#define EPI_BF16     1  // bf16 store of a
#define EPI_ELOGIT   2  // store exp(a*scale) bf16 + atomic row sums into lsum
#define EPI_PVOUT    3  // fp32 store of a/lsum[row] + bias[col]

#define FENCE() asm volatile("" ::: "memory")

#define MFMA_QUAD(mh, nh)                                                    \
    do {                                                                     \
        __builtin_amdgcn_s_setprio(1);                                       \
        _Pragma("unroll")                                                    \
        for (int ks = 0; ks < 2; ++ks)                                       \
            _Pragma("unroll")                                                \
            for (int q = 0; q < 4; ++q)                                      \
                _Pragma("unroll")                                            \
                for (int nn = 0; nn < 2; ++nn)                               \
                    acc[(mh) * 4 + q][(nh) * 2 + nn] =                       \
                        __builtin_amdgcn_mfma_f32_16x16x32_bf16(             \
                            aF[q][ks], bF[(nh) * 2 + nn][ks],                \
                            acc[(mh) * 4 + q][(nh) * 2 + nn], 0, 0, 0);      \
        __builtin_amdgcn_s_setprio(0);                                       \
    } while (0)

template<int EPI, int K, int LDA, int LDB, int LDC>
__global__ __launch_bounds__(512, 2) void gemm8w(
    const u16* __restrict__ A, const u16* __restrict__ Bt,
    const float* __restrict__ bias, u16* __restrict__ C,
    float* __restrict__ Cf, float* __restrict__ lsum,
    float scale, long sA, long sB, long sC)
{
    // [dbuf][mat(A/B)][half][128x64 bf16], swizzled. 128 KiB -> 1 block/CU.
    __shared__ u16 lds[2][2][2][8192];

    constexpr int NT = K / 64;      // half-iterations (one 64-wide K tile each)

    const int z = blockIdx.z;
    A  += (size_t)z * sA;
    Bt += (size_t)z * sB;

    const int t = threadIdx.x;                 // 0..511
    const int wid = t >> 6, lane = t & 63;
    const int wm = wid >> 2, wn = wid & 3;     // wave tile: 128x64 at (wm,wn)
    const int lrow = lane & 15, quad = lane >> 4;
    const int m0 = blockIdx.y * 256, n0 = blockIdx.x * 256;

    // ---- staging precompute: thread owns 2 x 16B chunks per half-tile ----
    // LDS dest is linear (global_load_lds constraint); the global SOURCE is
    // pre-swizzled with the same involution the reads use, so swizzled reads
    // see a linear-global layout. swz(b) = b ^ (((b>>7)&7)<<4): XOR 16B-chunk
    // bits 4-6 with row bits 0-2 (row stride 128B). Bits 7+ untouched by the
    // XOR => involution.
    int ldsoff[2], offA[2], offB[2];
    #pragma unroll
    for (int p = 0; p < 2; ++p) {
        const int L  = p * 8192 + wid * 1024 + lane * 16;
        const int sL = L ^ (((L >> 7) & 7) << 4);
        const int r  = sL >> 7;             // 0..127 (row within half)
        const int c  = (sL & 127) >> 1;     // bf16 col (multiple of 8)
        ldsoff[p] = L;
        offA[p]   = r * LDA + c;
        offB[p]   = r * LDB + c;
    }
    const u16* ABase = A  + (size_t)m0 * LDA;
    const u16* BBase = Bt + (size_t)n0 * LDB;

    // stage half-tile: sel 0=A-h0 1=A-h1 2=B-h0 3=B-h1, into buf = tile&1
    auto stage = [&](int tile, int sel) {
        const int mat = sel >> 1, half = sel & 1, buf = tile & 1;
        char* dst = (char*)&lds[buf][mat][half][0];
        const int k0 = tile * 64;
        #pragma unroll
        for (int p = 0; p < 2; ++p) {
            const u16* src = mat
                ? BBase + (size_t)half * (128 * (size_t)LDB) + k0 + offB[p]
                : ABase + (size_t)half * (128 * (size_t)LDA) + k0 + offA[p];
            async16(dst + ldsoff[p], src);
        }
    };

    f32x4 acc[8][4];
    #pragma unroll
    for (int i = 0; i < 8; ++i)
        #pragma unroll
        for (int j = 0; j < 4; ++j)
            acc[i][j] = (f32x4){0.f, 0.f, 0.f, 0.f};

    bf16x8 aF[4][2], bF[4][2];

    // swizzled ds_read of one 16x16x32 fragment (16B per lane)
    auto ldA1 = [&](int buf, int mi, int ks) -> bf16x8 {
        int b = (mi * 16 + lrow) * 128 + ks * 64 + quad * 16;
        b ^= ((b >> 7) & 7) << 4;
        return *(const bf16x8*)((const char*)&lds[buf][0][wm][0] + b);
    };
    auto ldB1 = [&](int buf, int ni, int ks) -> bf16x8 {
        int b = ((wn & 1) * 64 + ni * 16 + lrow) * 128 + ks * 64 + quad * 16;
        b ^= ((b >> 7) & 7) << 4;
        return *(const bf16x8*)((const char*)&lds[buf][1][wn >> 1][0] + b);
    };

    // ---- prologue: tile0 complete + tile1 {B-h0, B-h1, A-h0} in flight ----
    stage(0, 0); stage(0, 1); stage(0, 2); stage(0, 3);
    stage(1, 2); stage(1, 3); stage(1, 0);
    asm volatile("s_waitcnt vmcnt(6)" ::: "memory");   // tile0 resident
    __builtin_amdgcn_s_barrier();

    #pragma unroll 1
    for (int T = 0; T < NT; ++T) {
        const int buf = T & 1;
        const bool s1 = (T + 1 < NT), s2 = (T + 2 < NT);

        // -- pq0: read A rows 0-63 + ALL B; stage (T+1, A-h1) -> buf^1
        #pragma unroll
        for (int q = 0; q < 4; ++q) {
            aF[q][0] = ldA1(buf, q, 0);
            aF[q][1] = ldA1(buf, q, 1);
        }
        #pragma unroll
        for (int ni = 0; ni < 4; ++ni) {
            bF[ni][0] = ldB1(buf, ni, 0);
            bF[ni][1] = ldB1(buf, ni, 1);
        }
        if (s1) stage(T + 1, 1);
        FENCE(); __builtin_amdgcn_s_barrier();
        MFMA_QUAD(0, 0);
        FENCE(); __builtin_amdgcn_s_barrier();

        // -- pq1: MFMA only (uses bF[2..3], consumed here -> B slots free)
        MFMA_QUAD(0, 1);
        FENCE(); __builtin_amdgcn_s_barrier();

        // -- pq2: read A rows 64-127; stage (T+2, B-h0/B-h1) -> buf (safe)
        #pragma unroll
        for (int q = 0; q < 4; ++q) {
            aF[q][0] = ldA1(buf, 4 + q, 0);
            aF[q][1] = ldA1(buf, 4 + q, 1);
        }
        if (s2) { stage(T + 2, 2); stage(T + 2, 3); }
        FENCE(); __builtin_amdgcn_s_barrier();
        MFMA_QUAD(1, 1);
        FENCE(); __builtin_amdgcn_s_barrier();

        // -- pq3: stage (T+2, A-h0) -> buf (A free since pq2 barrier);
        //    counted vmcnt: retire through (T+1, A-h1) => tile T+1 resident,
        //    3 half-tiles of T+2 in flight. Tail: full drain.
        if (s2) {
            stage(T + 2, 0);
            asm volatile("s_waitcnt vmcnt(6)" ::: "memory");
        } else {
            asm volatile("s_waitcnt vmcnt(0)" ::: "memory");
        }
        FENCE(); __builtin_amdgcn_s_barrier();
        MFMA_QUAD(1, 0);
        FENCE(); __builtin_amdgcn_s_barrier();
    }

    // ---- epilogue ----
    if (EPI == EPI_PVOUT) Cf += (size_t)z * sC;
    else                  C  += (size_t)z * sC;

    #pragma unroll
    for (int mi = 0; mi < 8; ++mi) {
        const int row = m0 + wm * 128 + mi * 16 + quad * 4;  // rows row..row+3
        if (EPI == EPI_BF16BIAS) {
            #pragma unroll
            for (int ni = 0; ni < 4; ++ni) {
                const int col = n0 + wn * 64 + ni * 16 + lrow;
                const float bb = bias[col];
                const f32x4 a = acc[mi][ni];
                #pragma unroll
                for (int r = 0; r < 4; ++r)
                    C[(size_t)(row + r) * LDC + col] = f2bf(a[r] + bb);
            }
        } else if (EPI == EPI_BF16) {
            #pragma unroll
            for (int ni = 0; ni < 4; ++ni) {
                const int col = n0 + wn * 64 + ni * 16 + lrow;
                const f32x4 a = acc[mi][ni];
                #pragma unroll
                for (int r = 0; r < 4; ++r)
                    C[(size_t)(row + r) * LDC + col] = f2bf(a[r]);
            }
        } else if (EPI == EPI_ELOGIT) {
            float rs[4] = {0.f, 0.f, 0.f, 0.f};
            #pragma unroll
            for (int ni = 0; ni < 4; ++ni) {
                const int col = n0 + wn * 64 + ni * 16 + lrow;
                const f32x4 a = acc[mi][ni];
                #pragma unroll
                for (int r = 0; r < 4; ++r) {
                    const float e = __expf(a[r] * scale);
                    C[(size_t)(row + r) * LDC + col] = f2bf(e);
                    rs[r] += e;
                }
            }
            #pragma unroll
            for (int r = 0; r < 4; ++r) {
                float s = rs[r];
                s += __shfl_xor(s, 1, 64);
                s += __shfl_xor(s, 2, 64);
                s += __shfl_xor(s, 4, 64);
                s += __shfl_xor(s, 8, 64);
                if (lrow == 0)
                    atomicAdd(&lsum[(size_t)z * 2048 + row + r], s);
            }
        } else { // EPI_PVOUT
            float linv[4];
            #pragma unroll
            for (int r = 0; r < 4; ++r)
                linv[r] = 1.0f / lsum[(size_t)z * 2048 + row + r];
            #pragma unroll
            for (int ni = 0; ni < 4; ++ni) {
                const int col = n0 + wn * 64 + ni * 16 + lrow;
                const float bb = bias[col];
                const f32x4 a = acc[mi][ni];
                #pragma unroll
                for (int r = 0; r < 4; ++r)
                    Cf[(size_t)(row + r) * LDC + col] = a[r] * linv[r] + bb;
            }
        }
    }
}

// ---------------------------------------------------------------------------
extern "C" void kernel_launch(void* const* d_in, const int* in_sizes, int n_in,
                              void* d_out, int out_size, void* d_ws, size_t ws_size,
                              hipStream_t stream)
{
    const float* x  = (const float*)d_in[0];
    const float* wq = (const float*)d_in[1];
    const float* bq = (const float*)d_in[2];
    const float* wk = (const float*)d_in[3];
    const float* bk = (const float*)d_in[4];
    const float* wv = (const float*)d_in[5];
    const float* bv = (const float*)d_in[6];
    const float* wo = (const float*)d_in[7];
    const float* bo = (const float*)d_in[8];
    float* out = (float*)d_out;

    u16* w16   = (u16*)d_ws;
    u16* xb    = w16;
    u16* qkv   = w16 + 8388608;          // [8192][3072]; q|k|v at col 0/1024/2048
    u16* E     = w16 + 33554432;
    u16* wqkvT = w16 + 50331648;         // [3072][1024] = wqT|wkT|wvT
    u16* woT   = w16 + 53477376;
    float* bqkv = (float*)(w16 + 54525952);
    float* l    = (float*)(w16 + 54532096);
    u16* VWoT  = w16;                    // aliases xb (dead after QKV) [b][1024][2048]

    const u16* q_ = qkv;                 // LDA/LDB = 3072 views
    const u16* k_ = qkv + 1024;
    const u16* v_ = qkv + 2048;

    cast_x_kernel<<<8236, dim3(256), 0, stream>>>(x, xb, bq, bk, bv, bqkv, l);
    transpose_cast_all<<<dim3(32, 32, 4), dim3(32, 8), 0, stream>>>(
        wq, wk, wv, wo, wqkvT, woT);

    // fused QKV: qkv[8192,3072] = xb @ wqkvT^T + bqkv
    gemm8w<EPI_BF16BIAS, 1024, 1024, 1024, 3072>
        <<<dim3(12, 32, 1), dim3(512), 0, stream>>>(
            xb, wqkvT, bqkv, qkv, nullptr, nullptr, 1.f, 0, 0, 0);

    // E[z] = exp((q[z] @ k[z]^T)/32) bf16, + row sums into l
    gemm8w<EPI_ELOGIT, 1024, 3072, 3072, 2048>
        <<<dim3(8, 8, 4), dim3(512), 0, stream>>>(
            q_, k_, nullptr, E, nullptr, l, 0.03125f,
            6291456, 6291456, 4194304);

    // VWoT[z] = woT @ v[z]^T   [1024][2048] bf16 per batch
    gemm8w<EPI_BF16, 1024, 1024, 3072, 2048>
        <<<dim3(8, 4, 4), dim3(512), 0, stream>>>(
            woT, v_, nullptr, VWoT, nullptr, nullptr, 1.f,
            0, 6291456, 2097152);

    // out[z] = (E[z] @ VWoT[z]^T) / l + bo   fp32 [2048][1024] per batch
    gemm8w<EPI_PVOUT, 2048, 2048, 2048, 1024>
        <<<dim3(4, 8, 4), dim3(512), 0, stream>>>(
            E, VWoT, bo, nullptr, out, l, 1.f,
            4194304, 2097152, 2097152);
}